// Round 18
// baseline (780.512 us; speedup 1.0000x reference)
//
#include <hip/hip_runtime.h>
#include <hip/hip_bf16.h>

// B=4, S=8192 -> 32768 tokens; HID=1024; NH=DH=32.
// convw: Wq/Wk/Wv f32 -> bf16 in d_ws (2MB each)
// S1q: q=(query@Wq^T+bq)/32 -> bf16 @ dout_b[tok*2048 + n]
// S1k: k=(key@Wk^T+bk)      -> bf16 @ dout_b[tok*2048 + 1024 + n]
// S2 : per-token 32x32 scores + softmax over heads-t -> p bf16 @ d_ws
// S3 : v GEMM; epilogue out[idx] = p[idx] * (v+bv)
//
// gemm256 r18 = r13 (378us proven) + pipeline DEPTH+1 on both operands:
//  - A: two register sets ar0/ar1 (tile t -> set t&1 -> LDS A-buf t&1);
//    aload(kt+3) at iter kt, consumed at kt+2 (~2 iters slack vs HBM 900cy).
//    Static set selection via wave-uniform branch (rule #20).
//  - B: TRIPLE-buffered LDS; bstage(kt+2) at iter kt, drained at kt+1
//    bottom (1 full iter slack).
//  - LDS = 2x32KB (A) + 3x32KB (B) = 160KB exactly (AITER precedent).
//  - Counted vmcnt from pinned [bstage 4][aload 8] order:
//    kt<13: vmcnt(20); kt==13: vmcnt(12); kt==14: vmcnt(0).
//  Everything else (layouts, swizzles, epilogue, pins) = r13 verbatim.

typedef __attribute__((ext_vector_type(8))) short bf16x8;
typedef __attribute__((ext_vector_type(4))) float f32x4;

#define HID 1024

#define GLOAD_LDS16(gp, lp)                                                   \
  __builtin_amdgcn_global_load_lds(                                           \
      (const __attribute__((address_space(1))) void*)(gp),                    \
      (__attribute__((address_space(3))) void*)(lp), 16, 0, 0)

#define SBAR __builtin_amdgcn_sched_barrier(0)

__device__ __forceinline__ unsigned short f2bf(float f) {
  unsigned int u = __builtin_bit_cast(unsigned int, f);
  u += 0x7FFFu + ((u >> 16) & 1u);  // RTNE
  return (unsigned short)(u >> 16);
}
__device__ __forceinline__ float bf2f(unsigned short h) {
  unsigned int u = (unsigned int)h << 16;
  return __builtin_bit_cast(float, u);
}

__device__ __forceinline__ uint2 cvt4(f32x4 a) {
  uint2 r;
  asm("v_cvt_pk_bf16_f32 %0, %1, %2" : "=v"(r.x) : "v"(a[0]), "v"(a[1]));
  asm("v_cvt_pk_bf16_f32 %0, %1, %2" : "=v"(r.y) : "v"(a[2]), "v"(a[3]));
  return r;
}
__device__ __forceinline__ bf16x8 cvt8(f32x4 a, f32x4 b) {
  union { unsigned int u[4]; bf16x8 v; } r;
  asm("v_cvt_pk_bf16_f32 %0, %1, %2" : "=v"(r.u[0]) : "v"(a[0]), "v"(a[1]));
  asm("v_cvt_pk_bf16_f32 %0, %1, %2" : "=v"(r.u[1]) : "v"(a[2]), "v"(a[3]));
  asm("v_cvt_pk_bf16_f32 %0, %1, %2" : "=v"(r.u[2]) : "v"(b[0]), "v"(b[1]));
  asm("v_cvt_pk_bf16_f32 %0, %1, %2" : "=v"(r.u[3]) : "v"(b[2]), "v"(b[3]));
  return r.v;
}

// W f32 [1024][1024] -> bf16
__global__ __launch_bounds__(256)
void convw_kernel(const float* __restrict__ src, unsigned short* __restrict__ dst) {
  const int i = blockIdx.x * 256 + threadIdx.x;
  const f32x4 a = ((const f32x4*)src)[i * 2];
  const f32x4 b = ((const f32x4*)src)[i * 2 + 1];
  ((bf16x8*)dst)[i] = cvt8(a, b);
}

// out[m,n] = sum_k X[m,k]*W[n,k] + b[n];  X f32, Wb bf16.
template<int MODE>
__global__ __launch_bounds__(512, 1)
void gemm256(const float* __restrict__ X, const unsigned short* __restrict__ Wb,
             const float* __restrict__ bias, void* outp,
             const unsigned short* __restrict__ pbf) {
  // 512 blocks = 128 m-tiles x 4 n-tiles; XCD-chunked, n fastest.
  const int bid = blockIdx.x;
  const int L = (bid & 7) * 64 + (bid >> 3);
  const int m0 = (L >> 2) * 256;
  const int n0 = (L & 3) * 256;
  const int tid = threadIdx.x;
  const int lane = tid & 63;
  const int wid = tid >> 6;
  const int wm = (wid >> 2) * 128;       // 0 / 128
  const int wn = (wid & 3) * 64;         // 0..192
  const int lo = lane & 15, grp = lane >> 4;

  // A bf16 [256][128B]: buf0 @0, buf1 @32768.  B bf16 [256][128B]:
  // buf b @ 65536 + b*32768 (3 bufs). addr(row,s)=row*128+((s^(row&7))<<4).
  __shared__ __align__(16) unsigned char lds[163840];

  // ---- A staging (coalesced, r13 map): granule g = i*512+tid ----
  const char* Xc = (const char*)X;
  const int acg = tid & 15;
  size_t asrc[8]; int aldst[8];
#pragma unroll
  for (int i = 0; i < 8; ++i) {
    const int row = i * 32 + (tid >> 4);
    asrc[i] = (size_t)(m0 + row) * 4096 + (size_t)(acg * 16);
    aldst[i] = row * 128 + (((acg >> 1) ^ (row & 7)) << 4) + (acg & 1) * 8;
  }
  f32x4 ar0[8], ar1[8];                  // tile t -> set t&1
  auto aload0 = [&](int kt) {
    const size_t kb = (size_t)kt * 256;
#pragma unroll
    for (int i = 0; i < 8; ++i) ar0[i] = *(const f32x4*)(Xc + asrc[i] + kb);
  };
  auto aload1 = [&](int kt) {
    const size_t kb = (size_t)kt * 256;
#pragma unroll
    for (int i = 0; i < 8; ++i) ar1[i] = *(const f32x4*)(Xc + asrc[i] + kb);
  };
  auto awrite0 = [&]() {                 // set0 -> A-buf0
#pragma unroll
    for (int i = 0; i < 8; ++i) *(uint2*)&lds[aldst[i]] = cvt4(ar0[i]);
  };
  auto awrite1 = [&]() {                 // set1 -> A-buf1
#pragma unroll
    for (int i = 0; i < 8; ++i) *(uint2*)&lds[32768 + aldst[i]] = cvt4(ar1[i]);
  };

  // ---- B staging: global_load_lds, linear dest, pre-swizzled source ----
  const char* Wc = (const char*)Wb;
  size_t bsrc[4];
#pragma unroll
  for (int i = 0; i < 4; ++i) {
    const int g = tid + i * 512;          // granule 0..2047
    const int row = g >> 3, j = g & 7;
    bsrc[i] = (size_t)(n0 + row) * 2048 + (size_t)((j ^ (row & 7)) << 4);
  }
  auto bstage = [&](int b, int kt) {
    const size_t kb = (size_t)kt * 128;
    const int base = 65536 + b * 32768;
#pragma unroll
    for (int i = 0; i < 4; ++i)
      GLOAD_LDS16(Wc + bsrc[i] + kb, &lds[base + tid * 16 + i * 8192]);
  };

  f32x4 acc[8][4] = {};
  auto compute = [&](int ab, int bb) {
    const unsigned char* Ab = &lds[ab * 32768];
    const unsigned char* Bb = &lds[65536 + bb * 32768];
#pragma unroll
    for (int kk = 0; kk < 2; ++kk) {
      const int s = kk * 4 + grp;
      bf16x8 af[8], bfm[4];
#pragma unroll
      for (int f = 0; f < 8; ++f) {
        const int ra = wm + f * 16 + lo;
        af[f] = *(const bf16x8*)&Ab[ra * 128 + ((s ^ (ra & 7)) << 4)];
      }
#pragma unroll
      for (int g = 0; g < 4; ++g) {
        const int rb = wn + g * 16 + lo;
        bfm[g] = *(const bf16x8*)&Bb[rb * 128 + ((s ^ (rb & 7)) << 4)];
      }
      __builtin_amdgcn_s_setprio(1);
#pragma unroll
      for (int fm = 0; fm < 8; ++fm)
#pragma unroll
        for (int fn = 0; fn < 4; ++fn)
          acc[fm][fn] = __builtin_amdgcn_mfma_f32_16x16x32_bf16(
              af[fm], bfm[fn], acc[fm][fn], 0, 0, 0);
      __builtin_amdgcn_s_setprio(0);
    }
  };

  // Prologue: A(0) staged; B(0),B(1) + A(1),A(2) in flight. Order PINNED.
  aload0(0);
  awrite0();                 // implicit vmcnt for ar0
  SBAR;
  bstage(0, 0);
  bstage(1, 1);
  SBAR;                      // pin: [8 B-DMA] before [16 A-loads]
  aload1(1);
  aload0(2);
  SBAR;
  asm volatile("s_waitcnt vmcnt(20)" ::: "memory");  // drain B(0) exactly
  asm volatile("s_waitcnt lgkmcnt(0)" ::: "memory");
  __builtin_amdgcn_s_barrier();
  SBAR;

  int bb = 0;                // kt % 3
#pragma unroll 1
  for (int kt = 0; kt < 16; ++kt) {
    const int ab = kt & 1;
    if (kt < 15) {           // stage A(kt+1) into buf (kt+1)&1 from set (kt+1)&1
      if ((kt + 1) & 1) awrite1(); else awrite0();
      SBAR;                  // pin: ds_writes + ar reg-waits done
    }
    if (kt < 14) {           // B(kt+2) -> buf (kt+2)%3
      int b2 = bb + 2; if (b2 >= 3) b2 -= 3;
      bstage(b2, kt + 2);
      SBAR;                  // pin: B-DMA before A-loads
    }
    if (kt < 13) {           // A(kt+3) -> set (kt+3)&1
      if ((kt + 3) & 1) aload1(kt + 3); else aload0(kt + 3);
      SBAR;
    }
    compute(ab, bb);
    SBAR;
    // Drain B(kt+1) only; deeper loads stay in flight across the barrier.
    if (kt < 13)       asm volatile("s_waitcnt vmcnt(20)" ::: "memory");
    else if (kt == 13) asm volatile("s_waitcnt vmcnt(12)" ::: "memory");
    else if (kt == 14) asm volatile("s_waitcnt vmcnt(0)" ::: "memory");
    asm volatile("s_waitcnt lgkmcnt(0)" ::: "memory");
    __builtin_amdgcn_s_barrier();
    SBAR;
    ++bb; if (bb >= 3) bb = 0;
  }

  // Epilogue. C frag layout: col=lane&15, row=(lane>>4)*4+j (m89-verified).
  if (MODE == 2) {
    float* of = (float*)outp;
#pragma unroll
    for (int fm = 0; fm < 8; ++fm) {
      const int row = m0 + wm + fm * 16 + grp * 4;
#pragma unroll
      for (int fn = 0; fn < 4; ++fn) {
        const int col = n0 + wn + fn * 16 + lo;
        const float bc = bias[col];
#pragma unroll
        for (int j = 0; j < 4; ++j) {
          const size_t idx = (size_t)(row + j) * 1024 + col;
          of[idx] = bf2f(pbf[idx]) * (acc[fm][fn][j] + bc);
        }
      }
    }
  } else {
    const float scale = (MODE == 0) ? 0.03125f : 1.0f;
    unsigned short* lds16 = (unsigned short*)&lds[0];  // [128][256] u16
    unsigned short* ob = (unsigned short*)outp;
    const int half = (MODE == 1) ? 1024 : 0;
    float bcol[4];
#pragma unroll
    for (int fn = 0; fn < 4; ++fn) bcol[fn] = bias[n0 + wn + fn * 16 + lo];
#pragma unroll 1
    for (int h = 0; h < 2; ++h) {
      if ((wid >> 2) == h) {
#pragma unroll
        for (int fm = 0; fm < 8; ++fm)
#pragma unroll
          for (int fn = 0; fn < 4; ++fn)
#pragma unroll
            for (int j = 0; j < 4; ++j) {
              const int rl = fm * 16 + grp * 4 + j;          // 0..127
              const int col = wn + fn * 16 + lo;             // 0..255
              lds16[rl * 256 + (col ^ (grp << 4))] =
                  f2bf((acc[fm][fn][j] + bcol[fn]) * scale);
            }
      }
      __syncthreads();
      {
        const int row = tid >> 2;                  // 0..127
        const int c0 = (tid & 3) * 64;
        const int x = ((row >> 2) & 3) << 4;
#pragma unroll
        for (int q = 0; q < 8; ++q) {              // 8 x 8 u16 = full 64 cols
          const int cg = c0 + q * 8;
          const uint4 v = *(const uint4*)&lds16[row * 256 + (cg ^ x)];
          *(uint4*)&ob[(size_t)(m0 + h * 128 + row) * 2048 + half + n0 + cg] = v;
        }
      }
      __syncthreads();
    }
  }
}

// ---------- fallback GEMM (used only if ws too small) ----------
template<int MODE>
__global__ __launch_bounds__(256, 2)
void gemm_fb(const float* __restrict__ X, const float* __restrict__ W,
             const float* __restrict__ bias, void* outp,
             const unsigned short* __restrict__ pbf, int use_ws) {
  const int bid = blockIdx.x;
  const int L = (bid & 7) * 256 + (bid >> 3);
  const int m0 = (L >> 3) * 128;
  const int n0 = (L & 7) * 128;
  const int tid = threadIdx.x;
  const int lane = tid & 63;
  const int wid = tid >> 6;
  const int wm = (wid >> 1) << 6;
  const int wn = (wid & 1) << 6;
  const int lo = lane & 15, grp = lane >> 4;
  __shared__ __align__(16) unsigned char lds[2][32768];
  const int srow = tid >> 3;
  const int sk8  = tid & 7;
  const float* Ag = X + (size_t)(m0 + srow) * HID + sk8 * 8;
  const float* Bg = W + (size_t)(n0 + srow) * HID + sk8 * 8;
  f32x4 la[4][2], lb[4][2];
  auto gload = [&](int k0) {
#pragma unroll
    for (int rr = 0; rr < 4; ++rr) {
      const float* ap = Ag + (size_t)(rr * 32) * HID + k0;
      const float* bp = Bg + (size_t)(rr * 32) * HID + k0;
      la[rr][0] = *(const f32x4*)(ap); la[rr][1] = *(const f32x4*)(ap + 4);
      lb[rr][0] = *(const f32x4*)(bp); lb[rr][1] = *(const f32x4*)(bp + 4);
    }
  };
  auto cvtwrite = [&](int b) {
#pragma unroll
    for (int rr = 0; rr < 4; ++rr) {
      const int row = srow + rr * 32;
      const int adr = row * 128 + ((sk8 ^ (row & 7)) << 4);
      *(bf16x8*)&lds[b][adr]         = cvt8(la[rr][0], la[rr][1]);
      *(bf16x8*)&lds[b][16384 + adr] = cvt8(lb[rr][0], lb[rr][1]);
    }
  };
  f32x4 acc[4][4] = {};
  auto compute = [&](int b) {
#pragma unroll
    for (int kk = 0; kk < 2; ++kk) {
      const int slot = kk * 4 + grp;
      bf16x8 af[4], bfm[4];
#pragma unroll
      for (int f = 0; f < 4; ++f) {
        const int ra = wm + f * 16 + lo;
        const int rb = wn + f * 16 + lo;
        af[f]  = *(const bf16x8*)&lds[b][ra * 128 + ((slot ^ (ra & 7)) << 4)];
        bfm[f] = *(const bf16x8*)&lds[b][16384 + rb * 128 + ((slot ^ (rb & 7)) << 4)];
      }
#pragma unroll
      for (int fm = 0; fm < 4; ++fm)
#pragma unroll
        for (int fn = 0; fn < 4; ++fn)
          acc[fm][fn] = __builtin_amdgcn_mfma_f32_16x16x32_bf16(
              af[fm], bfm[fn], acc[fm][fn], 0, 0, 0);
    }
  };
  gload(0); cvtwrite(0); gload(64);
  SBAR;
  asm volatile("s_waitcnt lgkmcnt(0)" ::: "memory");
  __builtin_amdgcn_s_barrier();
  SBAR;
#pragma unroll 1
  for (int kt = 0; kt < 16; ++kt) {
    compute(kt & 1);
    if (kt < 15) {
      cvtwrite((kt + 1) & 1);
      if (kt < 14) gload((kt + 2) * 64);
    }
    SBAR;
    asm volatile("s_waitcnt lgkmcnt(0)" ::: "memory");
    __builtin_amdgcn_s_barrier();
    SBAR;
  }
  unsigned char* eb = &lds[0][0];
  const unsigned char* ebc = eb;
  if (MODE == 2) {
    float* of = (float*)outp;
#pragma unroll
    for (int fm = 0; fm < 4; ++fm) {
      const int row = m0 + wm + fm * 16 + grp * 4;
#pragma unroll
      for (int fn = 0; fn < 4; ++fn) {
        const int col = n0 + wn + fn * 16 + lo;
        const float bc = bias[col];
#pragma unroll
        for (int j = 0; j < 4; ++j) {
          const size_t idx = (size_t)(row + j) * 1024 + col;
          const float p = use_ws ? bf2f(pbf[idx]) : of[idx];
          of[idx] = p * (acc[fm][fn][j] + bc);
        }
      }
    }
  } else {
    const float scale = (MODE == 0) ? 0.03125f : 1.0f;
#pragma unroll
    for (int fm = 0; fm < 4; ++fm) {
#pragma unroll
      for (int fn = 0; fn < 4; ++fn) {
        const int colL = wn + fn * 16 + lo;
        const float bc = bias[n0 + colL];
#pragma unroll
        for (int j = 0; j < 4; ++j) {
          const int rowL = wm + fm * 16 + grp * 4 + j;
          const int byte = rowL * 256 + ((colL * 2) ^ ((rowL & 7) << 5));
          *(unsigned short*)&eb[byte] = f2bf((acc[fm][fn][j] + bc) * scale);
        }
      }
    }
    __syncthreads();
    unsigned short* ob = (unsigned short*)outp;
    const int half = (MODE == 1) ? 1024 : 0;
#pragma unroll
    for (int p = 0; p < 8; ++p) {
      const int r = p * 16 + (tid >> 4);
      const int c0 = (tid & 15) * 8;
      const uint4 v = *(const uint4*)&ebc[r * 256 + ((c0 * 2) ^ ((r & 7) << 5))];
      *(uint4*)&ob[(size_t)(m0 + r) * 2048 + half + n0 + c0] = v;
    }
  }
}

// S2: one wave per token. 32x32 scores via 4 MFMA, softmax over t (cols).
template<int PMODE>
__global__ __launch_bounds__(256)
void attn_kernel(float* __restrict__ dout, unsigned short* __restrict__ wsp) {
  const int wid = threadIdx.x >> 6;
  const int lane = threadIdx.x & 63;
  const int token = blockIdx.x * 4 + wid;
  const int lo = lane & 15, grp = lane >> 4;
  const unsigned short* qk = (const unsigned short*)dout + (size_t)token * 2048;
  const int base = lo * 32 + grp * 8;

  bf16x8 a0 = *(const bf16x8*)(qk + base);
  bf16x8 a1 = *(const bf16x8*)(qk + 512 + base);
  bf16x8 b0 = *(const bf16x8*)(qk + 1024 + base);
  bf16x8 b1 = *(const bf16x8*)(qk + 1536 + base);
  asm volatile("s_waitcnt vmcnt(0)" ::: "memory");

  const f32x4 z = {0.f, 0.f, 0.f, 0.f};
  f32x4 s[2][2];
  s[0][0] = __builtin_amdgcn_mfma_f32_16x16x32_bf16(a0, b0, z, 0, 0, 0);
  s[0][1] = __builtin_amdgcn_mfma_f32_16x16x32_bf16(a0, b1, z, 0, 0, 0);
  s[1][0] = __builtin_amdgcn_mfma_f32_16x16x32_bf16(a1, b0, z, 0, 0, 0);
  s[1][1] = __builtin_amdgcn_mfma_f32_16x16x32_bf16(a1, b1, z, 0, 0, 0);

  float* od = dout + (size_t)token * 1024;
  unsigned short* ob = wsp + (size_t)token * 1024;
#pragma unroll
  for (int rt = 0; rt < 2; ++rt) {
#pragma unroll
    for (int j = 0; j < 4; ++j) {
      const float v0 = s[rt][0][j], v1 = s[rt][1][j];
      float m = fmaxf(v0, v1);
#pragma unroll
      for (int msk = 1; msk < 16; msk <<= 1) m = fmaxf(m, __shfl_xor(m, msk, 64));
      const float e0 = __expf(v0 - m), e1 = __expf(v1 - m);
      float ssum = e0 + e1;
#pragma unroll
      for (int msk = 1; msk < 16; msk <<= 1) ssum += __shfl_xor(ssum, msk, 64);
      const float inv = 1.0f / ssum;
      const int h = rt * 16 + grp * 4 + j;
      if (PMODE == 0) {
        od[h * 32 + lo]      = e0 * inv;
        od[h * 32 + 16 + lo] = e1 * inv;
      } else {
        ob[h * 32 + lo]      = f2bf(e0 * inv);
        ob[h * 32 + 16 + lo] = f2bf(e1 * inv);
      }
    }
  }
}

extern "C" void kernel_launch(void* const* d_in, const int* in_sizes, int n_in,
                              void* d_out, int out_size, void* d_ws, size_t ws_size,
                              hipStream_t stream) {
  const float* query = (const float*)d_in[0];
  const float* key   = (const float*)d_in[1];
  const float* value = (const float*)d_in[2];
  const float* Wq    = (const float*)d_in[3];
  const float* bq    = (const float*)d_in[4];
  const float* Wk    = (const float*)d_in[5];
  const float* bk    = (const float*)d_in[6];
  const float* Wv    = (const float*)d_in[7];
  const float* bv    = (const float*)d_in[8];

  const size_t P_BYTES = (size_t)32768 * 1024 * 2;   // 64 MB (p bf16)
  const size_t W_BYTES = (size_t)1024 * 1024 * 2;    // 2 MB per W
  unsigned short* pbf = (unsigned short*)d_ws;
  unsigned short* Wqb = (unsigned short*)((char*)d_ws + P_BYTES);
  unsigned short* Wkb = Wqb + (W_BYTES / 2);
  unsigned short* Wvb = Wkb + (W_BYTES / 2);

  if (ws_size >= P_BYTES + 3 * W_BYTES) {
    convw_kernel<<<dim3(512), dim3(256), 0, stream>>>(Wq, Wqb);
    convw_kernel<<<dim3(512), dim3(256), 0, stream>>>(Wk, Wkb);
    convw_kernel<<<dim3(512), dim3(256), 0, stream>>>(Wv, Wvb);
    gemm256<0><<<dim3(512), dim3(512), 0, stream>>>(query, Wqb, bq, d_out, pbf);
    gemm256<1><<<dim3(512), dim3(512), 0, stream>>>(key,   Wkb, bk, d_out, pbf);
    attn_kernel<1><<<dim3(8192), dim3(256), 0, stream>>>((float*)d_out, pbf);
    gemm256<2><<<dim3(512), dim3(512), 0, stream>>>(value, Wvb, bv, d_out, pbf);
  } else {
    const int use_ws = (ws_size >= P_BYTES) ? 1 : 0;
    gemm_fb<0><<<dim3(2048), dim3(256), 0, stream>>>(query, Wq, bq, d_out, nullptr, 0);
    gemm_fb<1><<<dim3(2048), dim3(256), 0, stream>>>(key,   Wk, bk, d_out, nullptr, 0);
    if (use_ws)
      attn_kernel<1><<<dim3(8192), dim3(256), 0, stream>>>((float*)d_out, pbf);
    else
      attn_kernel<0><<<dim3(8192), dim3(256), 0, stream>>>((float*)d_out, nullptr);
    gemm_fb<2><<<dim3(2048), dim3(256), 0, stream>>>(value, Wv, bv, d_out, pbf, use_ws);
  }
}

// Round 19
// 378.071 us; speedup vs baseline: 2.0645x; 2.0645x over previous
//
#include <hip/hip_runtime.h>
#include <hip/hip_bf16.h>

// B=4, S=8192 -> 32768 tokens; HID=1024; NH=DH=32.
// convw: Wq/Wk/Wv f32 -> bf16 in d_ws (2MB each)
// S1q: q=(query@Wq^T+bq)/32 -> bf16 @ dout_b[tok*2048 + n]
// S1k: k=(key@Wk^T+bk)      -> bf16 @ dout_b[tok*2048 + 1024 + n]
// S2 : per-token 32x32 scores + softmax over heads-t -> p bf16 @ d_ws
// S3 : v GEMM; epilogue out[idx] = p[idx] * (v+bv)
//
// FINAL = r13 (session best, 378us, reproduced twice): 256² tile, BK=64,
// 8 waves (128x64 wave tile), bf16 LDS row*128+((s^(row&7))<<4) (0
// conflicts), coalesced A staging (4 rows x 256B/instr), B via
// global_load_lds w16 pre-swizzled source, ONE raw s_barrier per K-step,
// counted vmcnt(8) (never 0 mid-loop), staging groups sched_barrier(0)-
// pinned (vmcnt contract requires pinned VMEM issue order).
// Rejected by experiment: 4-phase split (r16, +barrier overhead at
// 1-blk/CU lockstep), LDS-depth+1 (r15, f32-A read cost), reg-depth+1
// (r18, VGPR overflow -> serialized loads), BK=32 2-blk/CU (r14, spill).

typedef __attribute__((ext_vector_type(8))) short bf16x8;
typedef __attribute__((ext_vector_type(4))) float f32x4;

#define HID 1024

#define GLOAD_LDS16(gp, lp)                                                   \
  __builtin_amdgcn_global_load_lds(                                           \
      (const __attribute__((address_space(1))) void*)(gp),                    \
      (__attribute__((address_space(3))) void*)(lp), 16, 0, 0)

#define SBAR __builtin_amdgcn_sched_barrier(0)

__device__ __forceinline__ unsigned short f2bf(float f) {
  unsigned int u = __builtin_bit_cast(unsigned int, f);
  u += 0x7FFFu + ((u >> 16) & 1u);  // RTNE
  return (unsigned short)(u >> 16);
}
__device__ __forceinline__ float bf2f(unsigned short h) {
  unsigned int u = (unsigned int)h << 16;
  return __builtin_bit_cast(float, u);
}

__device__ __forceinline__ uint2 cvt4(f32x4 a) {
  uint2 r;
  asm("v_cvt_pk_bf16_f32 %0, %1, %2" : "=v"(r.x) : "v"(a[0]), "v"(a[1]));
  asm("v_cvt_pk_bf16_f32 %0, %1, %2" : "=v"(r.y) : "v"(a[2]), "v"(a[3]));
  return r;
}
__device__ __forceinline__ bf16x8 cvt8(f32x4 a, f32x4 b) {
  union { unsigned int u[4]; bf16x8 v; } r;
  asm("v_cvt_pk_bf16_f32 %0, %1, %2" : "=v"(r.u[0]) : "v"(a[0]), "v"(a[1]));
  asm("v_cvt_pk_bf16_f32 %0, %1, %2" : "=v"(r.u[1]) : "v"(a[2]), "v"(a[3]));
  asm("v_cvt_pk_bf16_f32 %0, %1, %2" : "=v"(r.u[2]) : "v"(b[0]), "v"(b[1]));
  asm("v_cvt_pk_bf16_f32 %0, %1, %2" : "=v"(r.u[3]) : "v"(b[2]), "v"(b[3]));
  return r.v;
}

// W f32 [1024][1024] -> bf16
__global__ __launch_bounds__(256)
void convw_kernel(const float* __restrict__ src, unsigned short* __restrict__ dst) {
  const int i = blockIdx.x * 256 + threadIdx.x;
  const f32x4 a = ((const f32x4*)src)[i * 2];
  const f32x4 b = ((const f32x4*)src)[i * 2 + 1];
  ((bf16x8*)dst)[i] = cvt8(a, b);
}

// out[m,n] = sum_k X[m,k]*W[n,k] + b[n];  X f32, Wb bf16.
template<int MODE>
__global__ __launch_bounds__(512, 1)
void gemm256(const float* __restrict__ X, const unsigned short* __restrict__ Wb,
             const float* __restrict__ bias, void* outp,
             const unsigned short* __restrict__ pbf) {
  // 512 blocks = 128 m-tiles x 4 n-tiles; XCD-chunked, n fastest.
  const int bid = blockIdx.x;
  const int L = (bid & 7) * 64 + (bid >> 3);
  const int m0 = (L >> 2) * 256;
  const int n0 = (L & 3) * 256;
  const int tid = threadIdx.x;
  const int lane = tid & 63;
  const int wid = tid >> 6;
  const int wm = (wid >> 2) * 128;       // 0 / 128
  const int wn = (wid & 3) * 64;         // 0..192
  const int lo = lane & 15, grp = lane >> 4;

  // per buffer: A bf16 [256][128B] @0 (32KB), B bf16 [256][128B] @32768.
  // addr(row,s) = row*128 + ((s ^ (row&7))<<4), s = k/8 in 0..7.
  __shared__ __align__(16) unsigned char lds[2][65536];

  // ---- A staging (coalesced): granule g = i*512+tid; row=i*32+(tid>>4),
  // acg=tid&15 (16B f32). Per instr a wave covers 4 rows x 256B contiguous.
  const char* Xc = (const char*)X;
  const int acg = tid & 15;
  size_t asrc[8]; int aldst[8];
#pragma unroll
  for (int i = 0; i < 8; ++i) {
    const int row = i * 32 + (tid >> 4);
    asrc[i] = (size_t)(m0 + row) * 4096 + (size_t)(acg * 16);
    aldst[i] = row * 128 + (((acg >> 1) ^ (row & 7)) << 4) + (acg & 1) * 8;
  }
  f32x4 ar[8];
  auto aload = [&](int kt) {
    const size_t kb = (size_t)kt * 256;
#pragma unroll
    for (int i = 0; i < 8; ++i) ar[i] = *(const f32x4*)(Xc + asrc[i] + kb);
  };
  auto awrite = [&](int b) {
#pragma unroll
    for (int i = 0; i < 8; ++i) *(uint2*)&lds[b][aldst[i]] = cvt4(ar[i]);
  };

  // ---- B staging: global_load_lds, linear dest, pre-swizzled source ----
  const char* Wc = (const char*)Wb;
  size_t bsrc[4];
#pragma unroll
  for (int i = 0; i < 4; ++i) {
    const int g = tid + i * 512;          // granule 0..2047
    const int row = g >> 3, j = g & 7;
    bsrc[i] = (size_t)(n0 + row) * 2048 + (size_t)((j ^ (row & 7)) << 4);
  }
  auto bstage = [&](int b, int kt) {
    const size_t kb = (size_t)kt * 128;
#pragma unroll
    for (int i = 0; i < 4; ++i)
      GLOAD_LDS16(Wc + bsrc[i] + kb, &lds[b][32768 + tid * 16 + i * 8192]);
  };

  f32x4 acc[8][4] = {};
  auto compute = [&](int b) {
#pragma unroll
    for (int kk = 0; kk < 2; ++kk) {
      const int s = kk * 4 + grp;
      bf16x8 af[8], bfm[4];
#pragma unroll
      for (int f = 0; f < 8; ++f) {
        const int ra = wm + f * 16 + lo;
        af[f] = *(const bf16x8*)&lds[b][ra * 128 + ((s ^ (ra & 7)) << 4)];
      }
#pragma unroll
      for (int g = 0; g < 4; ++g) {
        const int rb = wn + g * 16 + lo;
        bfm[g] = *(const bf16x8*)&lds[b][32768 + rb * 128 + ((s ^ (rb & 7)) << 4)];
      }
      __builtin_amdgcn_s_setprio(1);
#pragma unroll
      for (int fm = 0; fm < 8; ++fm)
#pragma unroll
        for (int fn = 0; fn < 4; ++fn)
          acc[fm][fn] = __builtin_amdgcn_mfma_f32_16x16x32_bf16(
              af[fm], bfm[fn], acc[fm][fn], 0, 0, 0);
      __builtin_amdgcn_s_setprio(0);
    }
  };

  // Prologue: tile0 staged; aload(1) left in flight. Order PINNED.
  aload(0);
  awrite(0);                 // implicit vmcnt for ar
  SBAR;
  bstage(0, 0);
  SBAR;                      // pin: [bstage 4] before [aload 8]
  aload(1);
  SBAR;
  asm volatile("s_waitcnt vmcnt(8)" ::: "memory");  // drain bstage(0) exactly
  asm volatile("s_waitcnt lgkmcnt(0)" ::: "memory");
  __builtin_amdgcn_s_barrier();
  SBAR;

#pragma unroll 1
  for (int kt = 0; kt < 16; ++kt) {
    const int cur = kt & 1;
    if (kt < 15) {
      awrite(cur ^ 1);                    // consumes aload(kt+1) FIRST
      SBAR;                               // pin: ds_writes + ar-waits done
      bstage(cur ^ 1, kt + 1);            // 4 DMA issued...
      SBAR;                               // pin: ...BEFORE aload's 8
      if (kt < 14) aload(kt + 2);
      SBAR;                               // pin: staging order fixed
    }
    compute(cur);
    SBAR;
    if (kt < 14) asm volatile("s_waitcnt vmcnt(8)" ::: "memory");
    else         asm volatile("s_waitcnt vmcnt(0)" ::: "memory");
    asm volatile("s_waitcnt lgkmcnt(0)" ::: "memory");
    __builtin_amdgcn_s_barrier();
    SBAR;
  }

  // Epilogue. C frag layout: col=lane&15, row=(lane>>4)*4+j (m89-verified).
  if (MODE == 2) {
    float* of = (float*)outp;
#pragma unroll
    for (int fm = 0; fm < 8; ++fm) {
      const int row = m0 + wm + fm * 16 + grp * 4;
#pragma unroll
      for (int fn = 0; fn < 4; ++fn) {
        const int col = n0 + wn + fn * 16 + lo;
        const float bc = bias[col];
#pragma unroll
        for (int j = 0; j < 4; ++j) {
          const size_t idx = (size_t)(row + j) * 1024 + col;
          of[idx] = bf2f(pbf[idx]) * (acc[fm][fn][j] + bc);
        }
      }
    }
  } else {
    const float scale = (MODE == 0) ? 0.03125f : 1.0f;
    unsigned short* lds16 = (unsigned short*)&lds[0][0];  // [128][256]
    unsigned short* ob = (unsigned short*)outp;
    const int half = (MODE == 1) ? 1024 : 0;
    float bcol[4];
#pragma unroll
    for (int fn = 0; fn < 4; ++fn) bcol[fn] = bias[n0 + wn + fn * 16 + lo];
#pragma unroll 1
    for (int h = 0; h < 2; ++h) {
      if ((wid >> 2) == h) {
#pragma unroll
        for (int fm = 0; fm < 8; ++fm)
#pragma unroll
          for (int fn = 0; fn < 4; ++fn)
#pragma unroll
            for (int j = 0; j < 4; ++j) {
              const int rl = fm * 16 + grp * 4 + j;          // 0..127
              const int col = wn + fn * 16 + lo;             // 0..255
              lds16[rl * 256 + (col ^ (grp << 4))] =
                  f2bf((acc[fm][fn][j] + bcol[fn]) * scale);
            }
      }
      __syncthreads();
      {
        const int row = tid >> 2;                  // 0..127
        const int c0 = (tid & 3) * 64;
        const int x = ((row >> 2) & 3) << 4;
#pragma unroll
        for (int q = 0; q < 8; ++q) {              // 8 x 8 u16 = full 64 cols
          const int cg = c0 + q * 8;
          const uint4 v = *(const uint4*)&lds16[row * 256 + (cg ^ x)];
          *(uint4*)&ob[(size_t)(m0 + h * 128 + row) * 2048 + half + n0 + cg] = v;
        }
      }
      __syncthreads();
    }
  }
}

// ---------- fallback GEMM (used only if ws too small) ----------
template<int MODE>
__global__ __launch_bounds__(256, 2)
void gemm_fb(const float* __restrict__ X, const float* __restrict__ W,
             const float* __restrict__ bias, void* outp,
             const unsigned short* __restrict__ pbf, int use_ws) {
  const int bid = blockIdx.x;
  const int L = (bid & 7) * 256 + (bid >> 3);
  const int m0 = (L >> 3) * 128;
  const int n0 = (L & 7) * 128;
  const int tid = threadIdx.x;
  const int lane = tid & 63;
  const int wid = tid >> 6;
  const int wm = (wid >> 1) << 6;
  const int wn = (wid & 1) << 6;
  const int lo = lane & 15, grp = lane >> 4;
  __shared__ __align__(16) unsigned char lds[2][32768];
  const int srow = tid >> 3;
  const int sk8  = tid & 7;
  const float* Ag = X + (size_t)(m0 + srow) * HID + sk8 * 8;
  const float* Bg = W + (size_t)(n0 + srow) * HID + sk8 * 8;
  f32x4 la[4][2], lb[4][2];
  auto gload = [&](int k0) {
#pragma unroll
    for (int rr = 0; rr < 4; ++rr) {
      const float* ap = Ag + (size_t)(rr * 32) * HID + k0;
      const float* bp = Bg + (size_t)(rr * 32) * HID + k0;
      la[rr][0] = *(const f32x4*)(ap); la[rr][1] = *(const f32x4*)(ap + 4);
      lb[rr][0] = *(const f32x4*)(bp); lb[rr][1] = *(const f32x4*)(bp + 4);
    }
  };
  auto cvtwrite = [&](int b) {
#pragma unroll
    for (int rr = 0; rr < 4; ++rr) {
      const int row = srow + rr * 32;
      const int adr = row * 128 + ((sk8 ^ (row & 7)) << 4);
      *(bf16x8*)&lds[b][adr]         = cvt8(la[rr][0], la[rr][1]);
      *(bf16x8*)&lds[b][16384 + adr] = cvt8(lb[rr][0], lb[rr][1]);
    }
  };
  f32x4 acc[4][4] = {};
  auto compute = [&](int b) {
#pragma unroll
    for (int kk = 0; kk < 2; ++kk) {
      const int slot = kk * 4 + grp;
      bf16x8 af[4], bfm[4];
#pragma unroll
      for (int f = 0; f < 4; ++f) {
        const int ra = wm + f * 16 + lo;
        const int rb = wn + f * 16 + lo;
        af[f]  = *(const bf16x8*)&lds[b][ra * 128 + ((slot ^ (ra & 7)) << 4)];
        bfm[f] = *(const bf16x8*)&lds[b][16384 + rb * 128 + ((slot ^ (rb & 7)) << 4)];
      }
#pragma unroll
      for (int fm = 0; fm < 4; ++fm)
#pragma unroll
        for (int fn = 0; fn < 4; ++fn)
          acc[fm][fn] = __builtin_amdgcn_mfma_f32_16x16x32_bf16(
              af[fm], bfm[fn], acc[fm][fn], 0, 0, 0);
    }
  };
  gload(0); cvtwrite(0); gload(64);
  SBAR;
  asm volatile("s_waitcnt lgkmcnt(0)" ::: "memory");
  __builtin_amdgcn_s_barrier();
  SBAR;
#pragma unroll 1
  for (int kt = 0; kt < 16; ++kt) {
    compute(kt & 1);
    if (kt < 15) {
      cvtwrite((kt + 1) & 1);
      if (kt < 14) gload((kt + 2) * 64);
    }
    SBAR;
    asm volatile("s_waitcnt lgkmcnt(0)" ::: "memory");
    __builtin_amdgcn_s_barrier();
    SBAR;
  }
  unsigned char* eb = &lds[0][0];
  const unsigned char* ebc = eb;
  if (MODE == 2) {
    float* of = (float*)outp;
#pragma unroll
    for (int fm = 0; fm < 4; ++fm) {
      const int row = m0 + wm + fm * 16 + grp * 4;
#pragma unroll
      for (int fn = 0; fn < 4; ++fn) {
        const int col = n0 + wn + fn * 16 + lo;
        const float bc = bias[col];
#pragma unroll
        for (int j = 0; j < 4; ++j) {
          const size_t idx = (size_t)(row + j) * 1024 + col;
          const float p = use_ws ? bf2f(pbf[idx]) : of[idx];
          of[idx] = p * (acc[fm][fn][j] + bc);
        }
      }
    }
  } else {
    const float scale = (MODE == 0) ? 0.03125f : 1.0f;
#pragma unroll
    for (int fm = 0; fm < 4; ++fm) {
#pragma unroll
      for (int fn = 0; fn < 4; ++fn) {
        const int colL = wn + fn * 16 + lo;
        const float bc = bias[n0 + colL];
#pragma unroll
        for (int j = 0; j < 4; ++j) {
          const int rowL = wm + fm * 16 + grp * 4 + j;
          const int byte = rowL * 256 + ((colL * 2) ^ ((rowL & 7) << 5));
          *(unsigned short*)&eb[byte] = f2bf((acc[fm][fn][j] + bc) * scale);
        }
      }
    }
    __syncthreads();
    unsigned short* ob = (unsigned short*)outp;
    const int half = (MODE == 1) ? 1024 : 0;
#pragma unroll
    for (int p = 0; p < 8; ++p) {
      const int r = p * 16 + (tid >> 4);
      const int c0 = (tid & 15) * 8;
      const uint4 v = *(const uint4*)&ebc[r * 256 + ((c0 * 2) ^ ((r & 7) << 5))];
      *(uint4*)&ob[(size_t)(m0 + r) * 2048 + half + n0 + c0] = v;
    }
  }
}

// S2: one wave per token. 32x32 scores via 4 MFMA, softmax over t (cols).
template<int PMODE>
__global__ __launch_bounds__(256)
void attn_kernel(float* __restrict__ dout, unsigned short* __restrict__ wsp) {
  const int wid = threadIdx.x >> 6;
  const int lane = threadIdx.x & 63;
  const int token = blockIdx.x * 4 + wid;
  const int lo = lane & 15, grp = lane >> 4;
  const unsigned short* qk = (const unsigned short*)dout + (size_t)token * 2048;
  const int base = lo * 32 + grp * 8;

  bf16x8 a0 = *(const bf16x8*)(qk + base);
  bf16x8 a1 = *(const bf16x8*)(qk + 512 + base);
  bf16x8 b0 = *(const bf16x8*)(qk + 1024 + base);
  bf16x8 b1 = *(const bf16x8*)(qk + 1536 + base);
  asm volatile("s_waitcnt vmcnt(0)" ::: "memory");

  const f32x4 z = {0.f, 0.f, 0.f, 0.f};
  f32x4 s[2][2];
  s[0][0] = __builtin_amdgcn_mfma_f32_16x16x32_bf16(a0, b0, z, 0, 0, 0);
  s[0][1] = __builtin_amdgcn_mfma_f32_16x16x32_bf16(a0, b1, z, 0, 0, 0);
  s[1][0] = __builtin_amdgcn_mfma_f32_16x16x32_bf16(a1, b0, z, 0, 0, 0);
  s[1][1] = __builtin_amdgcn_mfma_f32_16x16x32_bf16(a1, b1, z, 0, 0, 0);

  float* od = dout + (size_t)token * 1024;
  unsigned short* ob = wsp + (size_t)token * 1024;
#pragma unroll
  for (int rt = 0; rt < 2; ++rt) {
#pragma unroll
    for (int j = 0; j < 4; ++j) {
      const float v0 = s[rt][0][j], v1 = s[rt][1][j];
      float m = fmaxf(v0, v1);
#pragma unroll
      for (int msk = 1; msk < 16; msk <<= 1) m = fmaxf(m, __shfl_xor(m, msk, 64));
      const float e0 = __expf(v0 - m), e1 = __expf(v1 - m);
      float ssum = e0 + e1;
#pragma unroll
      for (int msk = 1; msk < 16; msk <<= 1) ssum += __shfl_xor(ssum, msk, 64);
      const float inv = 1.0f / ssum;
      const int h = rt * 16 + grp * 4 + j;
      if (PMODE == 0) {
        od[h * 32 + lo]      = e0 * inv;
        od[h * 32 + 16 + lo] = e1 * inv;
      } else {
        ob[h * 32 + lo]      = f2bf(e0 * inv);
        ob[h * 32 + 16 + lo] = f2bf(e1 * inv);
      }
    }
  }
}

extern "C" void kernel_launch(void* const* d_in, const int* in_sizes, int n_in,
                              void* d_out, int out_size, void* d_ws, size_t ws_size,
                              hipStream_t stream) {
  const float* query = (const float*)d_in[0];
  const float* key   = (const float*)d_in[1];
  const float* value = (const float*)d_in[2];
  const float* Wq    = (const float*)d_in[3];
  const float* bq    = (const float*)d_in[4];
  const float* Wk    = (const float*)d_in[5];
  const float* bk    = (const float*)d_in[6];
  const float* Wv    = (const float*)d_in[7];
  const float* bv    = (const float*)d_in[8];

  const size_t P_BYTES = (size_t)32768 * 1024 * 2;   // 64 MB (p bf16)
  const size_t W_BYTES = (size_t)1024 * 1024 * 2;    // 2 MB per W
  unsigned short* pbf = (unsigned short*)d_ws;
  unsigned short* Wqb = (unsigned short*)((char*)d_ws + P_BYTES);
  unsigned short* Wkb = Wqb + (W_BYTES / 2);
  unsigned short* Wvb = Wkb + (W_BYTES / 2);

  if (ws_size >= P_BYTES + 3 * W_BYTES) {
    convw_kernel<<<dim3(512), dim3(256), 0, stream>>>(Wq, Wqb);
    convw_kernel<<<dim3(512), dim3(256), 0, stream>>>(Wk, Wkb);
    convw_kernel<<<dim3(512), dim3(256), 0, stream>>>(Wv, Wvb);
    gemm256<0><<<dim3(512), dim3(512), 0, stream>>>(query, Wqb, bq, d_out, pbf);
    gemm256<1><<<dim3(512), dim3(512), 0, stream>>>(key,   Wkb, bk, d_out, pbf);
    attn_kernel<1><<<dim3(8192), dim3(256), 0, stream>>>((float*)d_out, pbf);
    gemm256<2><<<dim3(512), dim3(512), 0, stream>>>(value, Wvb, bv, d_out, pbf);
  } else {
    const int use_ws = (ws_size >= P_BYTES) ? 1 : 0;
    gemm_fb<0><<<dim3(2048), dim3(256), 0, stream>>>(query, Wq, bq, d_out, nullptr, 0);
    gemm_fb<1><<<dim3(2048), dim3(256), 0, stream>>>(key,   Wk, bk, d_out, nullptr, 0);
    if (use_ws)
      attn_kernel<1><<<dim3(8192), dim3(256), 0, stream>>>((float*)d_out, pbf);
    else
      attn_kernel<0><<<dim3(8192), dim3(256), 0, stream>>>((float*)d_out, nullptr);
    gemm_fb<2><<<dim3(2048), dim3(256), 0, stream>>>(value, Wv, bv, d_out, pbf, use_ws);
  }
}

// Round 20
// 373.887 us; speedup vs baseline: 2.0876x; 1.0112x over previous
//
#include <hip/hip_runtime.h>
#include <hip/hip_bf16.h>

// B=4, S=8192 -> 32768 tokens; HID=1024; NH=DH=32.
// convw3: Wq/Wk/Wv f32 -> bf16 in d_ws (one 1536-block launch)
// S1q: q=(query@Wq^T+bq)/32 -> bf16 @ dout_b[tok*2048 + n]
// S1k: k=(key@Wk^T+bk)      -> bf16 @ dout_b[tok*2048 + 1024 + n]
// S2 : per-token 32x32 scores + softmax over heads-t -> p bf16 @ d_ws
// S3 : v GEMM; epilogue out[idx] = p[idx] * (v+bv)
//
// FINAL GEMM = r13 (session best, 378us, reproduced 3x): 256² tile, BK=64,
// 8 waves (128x64 wave tile), bf16 LDS row*128+((s^(row&7))<<4) (0
// conflicts), coalesced A staging (4 rows x 256B/instr), B via
// global_load_lds w16 pre-swizzled source, ONE raw s_barrier per K-step,
// counted vmcnt(8) (never 0 mid-loop), staging groups sched_barrier(0)-
// pinned (vmcnt contract requires pinned VMEM issue order).
// Rejected by experiment: 4-phase split (r16), LDS-depth+1 (r15),
// reg-depth+1 (r18, VGPR overflow), BK=32 2-blk/CU (r14, spill).
// r19 delta: convw x3 merged into one launch (dispatch plumbing only).

typedef __attribute__((ext_vector_type(8))) short bf16x8;
typedef __attribute__((ext_vector_type(4))) float f32x4;

#define HID 1024

#define GLOAD_LDS16(gp, lp)                                                   \
  __builtin_amdgcn_global_load_lds(                                           \
      (const __attribute__((address_space(1))) void*)(gp),                    \
      (__attribute__((address_space(3))) void*)(lp), 16, 0, 0)

#define SBAR __builtin_amdgcn_sched_barrier(0)

__device__ __forceinline__ unsigned short f2bf(float f) {
  unsigned int u = __builtin_bit_cast(unsigned int, f);
  u += 0x7FFFu + ((u >> 16) & 1u);  // RTNE
  return (unsigned short)(u >> 16);
}
__device__ __forceinline__ float bf2f(unsigned short h) {
  unsigned int u = (unsigned int)h << 16;
  return __builtin_bit_cast(float, u);
}

__device__ __forceinline__ uint2 cvt4(f32x4 a) {
  uint2 r;
  asm("v_cvt_pk_bf16_f32 %0, %1, %2" : "=v"(r.x) : "v"(a[0]), "v"(a[1]));
  asm("v_cvt_pk_bf16_f32 %0, %1, %2" : "=v"(r.y) : "v"(a[2]), "v"(a[3]));
  return r;
}
__device__ __forceinline__ bf16x8 cvt8(f32x4 a, f32x4 b) {
  union { unsigned int u[4]; bf16x8 v; } r;
  asm("v_cvt_pk_bf16_f32 %0, %1, %2" : "=v"(r.u[0]) : "v"(a[0]), "v"(a[1]));
  asm("v_cvt_pk_bf16_f32 %0, %1, %2" : "=v"(r.u[1]) : "v"(a[2]), "v"(a[3]));
  asm("v_cvt_pk_bf16_f32 %0, %1, %2" : "=v"(r.u[2]) : "v"(b[0]), "v"(b[1]));
  asm("v_cvt_pk_bf16_f32 %0, %1, %2" : "=v"(r.u[3]) : "v"(b[2]), "v"(b[3]));
  return r.v;
}

// Wq/Wk/Wv f32 [1024][1024] -> bf16, one launch (1536 blocks of 256).
__global__ __launch_bounds__(256)
void convw3_kernel(const float* __restrict__ s0, const float* __restrict__ s1,
                   const float* __restrict__ s2, unsigned short* __restrict__ d0,
                   unsigned short* __restrict__ d1, unsigned short* __restrict__ d2) {
  const int w = blockIdx.x >> 9;               // 0,1,2 (wave-uniform)
  const int i = (blockIdx.x & 511) * 256 + threadIdx.x;
  const float* src = (w == 0) ? s0 : (w == 1) ? s1 : s2;
  unsigned short* dst = (w == 0) ? d0 : (w == 1) ? d1 : d2;
  const f32x4 a = ((const f32x4*)src)[i * 2];
  const f32x4 b = ((const f32x4*)src)[i * 2 + 1];
  ((bf16x8*)dst)[i] = cvt8(a, b);
}

// out[m,n] = sum_k X[m,k]*W[n,k] + b[n];  X f32, Wb bf16.
template<int MODE>
__global__ __launch_bounds__(512, 1)
void gemm256(const float* __restrict__ X, const unsigned short* __restrict__ Wb,
             const float* __restrict__ bias, void* outp,
             const unsigned short* __restrict__ pbf) {
  // 512 blocks = 128 m-tiles x 4 n-tiles; XCD-chunked, n fastest.
  const int bid = blockIdx.x;
  const int L = (bid & 7) * 64 + (bid >> 3);
  const int m0 = (L >> 2) * 256;
  const int n0 = (L & 3) * 256;
  const int tid = threadIdx.x;
  const int lane = tid & 63;
  const int wid = tid >> 6;
  const int wm = (wid >> 2) * 128;       // 0 / 128
  const int wn = (wid & 3) * 64;         // 0..192
  const int lo = lane & 15, grp = lane >> 4;

  // per buffer: A bf16 [256][128B] @0 (32KB), B bf16 [256][128B] @32768.
  // addr(row,s) = row*128 + ((s ^ (row&7))<<4), s = k/8 in 0..7.
  __shared__ __align__(16) unsigned char lds[2][65536];

  // ---- A staging (coalesced): granule g = i*512+tid; row=i*32+(tid>>4),
  // acg=tid&15 (16B f32). Per instr a wave covers 4 rows x 256B contiguous.
  const char* Xc = (const char*)X;
  const int acg = tid & 15;
  size_t asrc[8]; int aldst[8];
#pragma unroll
  for (int i = 0; i < 8; ++i) {
    const int row = i * 32 + (tid >> 4);
    asrc[i] = (size_t)(m0 + row) * 4096 + (size_t)(acg * 16);
    aldst[i] = row * 128 + (((acg >> 1) ^ (row & 7)) << 4) + (acg & 1) * 8;
  }
  f32x4 ar[8];
  auto aload = [&](int kt) {
    const size_t kb = (size_t)kt * 256;
#pragma unroll
    for (int i = 0; i < 8; ++i) ar[i] = *(const f32x4*)(Xc + asrc[i] + kb);
  };
  auto awrite = [&](int b) {
#pragma unroll
    for (int i = 0; i < 8; ++i) *(uint2*)&lds[b][aldst[i]] = cvt4(ar[i]);
  };

  // ---- B staging: global_load_lds, linear dest, pre-swizzled source ----
  const char* Wc = (const char*)Wb;
  size_t bsrc[4];
#pragma unroll
  for (int i = 0; i < 4; ++i) {
    const int g = tid + i * 512;          // granule 0..2047
    const int row = g >> 3, j = g & 7;
    bsrc[i] = (size_t)(n0 + row) * 2048 + (size_t)((j ^ (row & 7)) << 4);
  }
  auto bstage = [&](int b, int kt) {
    const size_t kb = (size_t)kt * 128;
#pragma unroll
    for (int i = 0; i < 4; ++i)
      GLOAD_LDS16(Wc + bsrc[i] + kb, &lds[b][32768 + tid * 16 + i * 8192]);
  };

  f32x4 acc[8][4] = {};
  auto compute = [&](int b) {
#pragma unroll
    for (int kk = 0; kk < 2; ++kk) {
      const int s = kk * 4 + grp;
      bf16x8 af[8], bfm[4];
#pragma unroll
      for (int f = 0; f < 8; ++f) {
        const int ra = wm + f * 16 + lo;
        af[f] = *(const bf16x8*)&lds[b][ra * 128 + ((s ^ (ra & 7)) << 4)];
      }
#pragma unroll
      for (int g = 0; g < 4; ++g) {
        const int rb = wn + g * 16 + lo;
        bfm[g] = *(const bf16x8*)&lds[b][32768 + rb * 128 + ((s ^ (rb & 7)) << 4)];
      }
      __builtin_amdgcn_s_setprio(1);
#pragma unroll
      for (int fm = 0; fm < 8; ++fm)
#pragma unroll
        for (int fn = 0; fn < 4; ++fn)
          acc[fm][fn] = __builtin_amdgcn_mfma_f32_16x16x32_bf16(
              af[fm], bfm[fn], acc[fm][fn], 0, 0, 0);
      __builtin_amdgcn_s_setprio(0);
    }
  };

  // Prologue: tile0 staged; aload(1) left in flight. Order PINNED.
  aload(0);
  awrite(0);                 // implicit vmcnt for ar
  SBAR;
  bstage(0, 0);
  SBAR;                      // pin: [bstage 4] before [aload 8]
  aload(1);
  SBAR;
  asm volatile("s_waitcnt vmcnt(8)" ::: "memory");  // drain bstage(0) exactly
  asm volatile("s_waitcnt lgkmcnt(0)" ::: "memory");
  __builtin_amdgcn_s_barrier();
  SBAR;

#pragma unroll 1
  for (int kt = 0; kt < 16; ++kt) {
    const int cur = kt & 1;
    if (kt < 15) {
      awrite(cur ^ 1);                    // consumes aload(kt+1) FIRST
      SBAR;                               // pin: ds_writes + ar-waits done
      bstage(cur ^ 1, kt + 1);            // 4 DMA issued...
      SBAR;                               // pin: ...BEFORE aload's 8
      if (kt < 14) aload(kt + 2);
      SBAR;                               // pin: staging order fixed
    }
    compute(cur);
    SBAR;
    if (kt < 14) asm volatile("s_waitcnt vmcnt(8)" ::: "memory");
    else         asm volatile("s_waitcnt vmcnt(0)" ::: "memory");
    asm volatile("s_waitcnt lgkmcnt(0)" ::: "memory");
    __builtin_amdgcn_s_barrier();
    SBAR;
  }

  // Epilogue. C frag layout: col=lane&15, row=(lane>>4)*4+j (m89-verified).
  if (MODE == 2) {
    float* of = (float*)outp;
#pragma unroll
    for (int fm = 0; fm < 8; ++fm) {
      const int row = m0 + wm + fm * 16 + grp * 4;
#pragma unroll
      for (int fn = 0; fn < 4; ++fn) {
        const int col = n0 + wn + fn * 16 + lo;
        const float bc = bias[col];
#pragma unroll
        for (int j = 0; j < 4; ++j) {
          const size_t idx = (size_t)(row + j) * 1024 + col;
          of[idx] = bf2f(pbf[idx]) * (acc[fm][fn][j] + bc);
        }
      }
    }
  } else {
    const float scale = (MODE == 0) ? 0.03125f : 1.0f;
    unsigned short* lds16 = (unsigned short*)&lds[0][0];  // [128][256]
    unsigned short* ob = (unsigned short*)outp;
    const int half = (MODE == 1) ? 1024 : 0;
    float bcol[4];
#pragma unroll
    for (int fn = 0; fn < 4; ++fn) bcol[fn] = bias[n0 + wn + fn * 16 + lo];
#pragma unroll 1
    for (int h = 0; h < 2; ++h) {
      if ((wid >> 2) == h) {
#pragma unroll
        for (int fm = 0; fm < 8; ++fm)
#pragma unroll
          for (int fn = 0; fn < 4; ++fn)
#pragma unroll
            for (int j = 0; j < 4; ++j) {
              const int rl = fm * 16 + grp * 4 + j;          // 0..127
              const int col = wn + fn * 16 + lo;             // 0..255
              lds16[rl * 256 + (col ^ (grp << 4))] =
                  f2bf((acc[fm][fn][j] + bcol[fn]) * scale);
            }
      }
      __syncthreads();
      {
        const int row = tid >> 2;                  // 0..127
        const int c0 = (tid & 3) * 64;
        const int x = ((row >> 2) & 3) << 4;
#pragma unroll
        for (int q = 0; q < 8; ++q) {              // 8 x 8 u16 = full 64 cols
          const int cg = c0 + q * 8;
          const uint4 v = *(const uint4*)&lds16[row * 256 + (cg ^ x)];
          *(uint4*)&ob[(size_t)(m0 + h * 128 + row) * 2048 + half + n0 + cg] = v;
        }
      }
      __syncthreads();
    }
  }
}

// ---------- fallback GEMM (used only if ws too small) ----------
template<int MODE>
__global__ __launch_bounds__(256, 2)
void gemm_fb(const float* __restrict__ X, const float* __restrict__ W,
             const float* __restrict__ bias, void* outp,
             const unsigned short* __restrict__ pbf, int use_ws) {
  const int bid = blockIdx.x;
  const int L = (bid & 7) * 256 + (bid >> 3);
  const int m0 = (L >> 3) * 128;
  const int n0 = (L & 7) * 128;
  const int tid = threadIdx.x;
  const int lane = tid & 63;
  const int wid = tid >> 6;
  const int wm = (wid >> 1) << 6;
  const int wn = (wid & 1) << 6;
  const int lo = lane & 15, grp = lane >> 4;
  __shared__ __align__(16) unsigned char lds[2][32768];
  const int srow = tid >> 3;
  const int sk8  = tid & 7;
  const float* Ag = X + (size_t)(m0 + srow) * HID + sk8 * 8;
  const float* Bg = W + (size_t)(n0 + srow) * HID + sk8 * 8;
  f32x4 la[4][2], lb[4][2];
  auto gload = [&](int k0) {
#pragma unroll
    for (int rr = 0; rr < 4; ++rr) {
      const float* ap = Ag + (size_t)(rr * 32) * HID + k0;
      const float* bp = Bg + (size_t)(rr * 32) * HID + k0;
      la[rr][0] = *(const f32x4*)(ap); la[rr][1] = *(const f32x4*)(ap + 4);
      lb[rr][0] = *(const f32x4*)(bp); lb[rr][1] = *(const f32x4*)(bp + 4);
    }
  };
  auto cvtwrite = [&](int b) {
#pragma unroll
    for (int rr = 0; rr < 4; ++rr) {
      const int row = srow + rr * 32;
      const int adr = row * 128 + ((sk8 ^ (row & 7)) << 4);
      *(bf16x8*)&lds[b][adr]         = cvt8(la[rr][0], la[rr][1]);
      *(bf16x8*)&lds[b][16384 + adr] = cvt8(lb[rr][0], lb[rr][1]);
    }
  };
  f32x4 acc[4][4] = {};
  auto compute = [&](int b) {
#pragma unroll
    for (int kk = 0; kk < 2; ++kk) {
      const int slot = kk * 4 + grp;
      bf16x8 af[4], bfm[4];
#pragma unroll
      for (int f = 0; f < 4; ++f) {
        const int ra = wm + f * 16 + lo;
        const int rb = wn + f * 16 + lo;
        af[f]  = *(const bf16x8*)&lds[b][ra * 128 + ((slot ^ (ra & 7)) << 4)];
        bfm[f] = *(const bf16x8*)&lds[b][16384 + rb * 128 + ((slot ^ (rb & 7)) << 4)];
      }
#pragma unroll
      for (int fm = 0; fm < 4; ++fm)
#pragma unroll
        for (int fn = 0; fn < 4; ++fn)
          acc[fm][fn] = __builtin_amdgcn_mfma_f32_16x16x32_bf16(
              af[fm], bfm[fn], acc[fm][fn], 0, 0, 0);
    }
  };
  gload(0); cvtwrite(0); gload(64);
  SBAR;
  asm volatile("s_waitcnt lgkmcnt(0)" ::: "memory");
  __builtin_amdgcn_s_barrier();
  SBAR;
#pragma unroll 1
  for (int kt = 0; kt < 16; ++kt) {
    compute(kt & 1);
    if (kt < 15) {
      cvtwrite((kt + 1) & 1);
      if (kt < 14) gload((kt + 2) * 64);
    }
    SBAR;
    asm volatile("s_waitcnt lgkmcnt(0)" ::: "memory");
    __builtin_amdgcn_s_barrier();
    SBAR;
  }
  unsigned char* eb = &lds[0][0];
  const unsigned char* ebc = eb;
  if (MODE == 2) {
    float* of = (float*)outp;
#pragma unroll
    for (int fm = 0; fm < 4; ++fm) {
      const int row = m0 + wm + fm * 16 + grp * 4;
#pragma unroll
      for (int fn = 0; fn < 4; ++fn) {
        const int col = n0 + wn + fn * 16 + lo;
        const float bc = bias[col];
#pragma unroll
        for (int j = 0; j < 4; ++j) {
          const size_t idx = (size_t)(row + j) * 1024 + col;
          const float p = use_ws ? bf2f(pbf[idx]) : of[idx];
          of[idx] = p * (acc[fm][fn][j] + bc);
        }
      }
    }
  } else {
    const float scale = (MODE == 0) ? 0.03125f : 1.0f;
#pragma unroll
    for (int fm = 0; fm < 4; ++fm) {
#pragma unroll
      for (int fn = 0; fn < 4; ++fn) {
        const int colL = wn + fn * 16 + lo;
        const float bc = bias[n0 + colL];
#pragma unroll
        for (int j = 0; j < 4; ++j) {
          const int rowL = wm + fm * 16 + grp * 4 + j;
          const int byte = rowL * 256 + ((colL * 2) ^ ((rowL & 7) << 5));
          *(unsigned short*)&eb[byte] = f2bf((acc[fm][fn][j] + bc) * scale);
        }
      }
    }
    __syncthreads();
    unsigned short* ob = (unsigned short*)outp;
    const int half = (MODE == 1) ? 1024 : 0;
#pragma unroll
    for (int p = 0; p < 8; ++p) {
      const int r = p * 16 + (tid >> 4);
      const int c0 = (tid & 15) * 8;
      const uint4 v = *(const uint4*)&ebc[r * 256 + ((c0 * 2) ^ ((r & 7) << 5))];
      *(uint4*)&ob[(size_t)(m0 + r) * 2048 + half + n0 + c0] = v;
    }
  }
}

// S2: one wave per token. 32x32 scores via 4 MFMA, softmax over t (cols).
template<int PMODE>
__global__ __launch_bounds__(256)
void attn_kernel(float* __restrict__ dout, unsigned short* __restrict__ wsp) {
  const int wid = threadIdx.x >> 6;
  const int lane = threadIdx.x & 63;
  const int token = blockIdx.x * 4 + wid;
  const int lo = lane & 15, grp = lane >> 4;
  const unsigned short* qk = (const unsigned short*)dout + (size_t)token * 2048;
  const int base = lo * 32 + grp * 8;

  bf16x8 a0 = *(const bf16x8*)(qk + base);
  bf16x8 a1 = *(const bf16x8*)(qk + 512 + base);
  bf16x8 b0 = *(const bf16x8*)(qk + 1024 + base);
  bf16x8 b1 = *(const bf16x8*)(qk + 1536 + base);
  asm volatile("s_waitcnt vmcnt(0)" ::: "memory");

  const f32x4 z = {0.f, 0.f, 0.f, 0.f};
  f32x4 s[2][2];
  s[0][0] = __builtin_amdgcn_mfma_f32_16x16x32_bf16(a0, b0, z, 0, 0, 0);
  s[0][1] = __builtin_amdgcn_mfma_f32_16x16x32_bf16(a0, b1, z, 0, 0, 0);
  s[1][0] = __builtin_amdgcn_mfma_f32_16x16x32_bf16(a1, b0, z, 0, 0, 0);
  s[1][1] = __builtin_amdgcn_mfma_f32_16x16x32_bf16(a1, b1, z, 0, 0, 0);

  float* od = dout + (size_t)token * 1024;
  unsigned short* ob = wsp + (size_t)token * 1024;
#pragma unroll
  for (int rt = 0; rt < 2; ++rt) {
#pragma unroll
    for (int j = 0; j < 4; ++j) {
      const float v0 = s[rt][0][j], v1 = s[rt][1][j];
      float m = fmaxf(v0, v1);
#pragma unroll
      for (int msk = 1; msk < 16; msk <<= 1) m = fmaxf(m, __shfl_xor(m, msk, 64));
      const float e0 = __expf(v0 - m), e1 = __expf(v1 - m);
      float ssum = e0 + e1;
#pragma unroll
      for (int msk = 1; msk < 16; msk <<= 1) ssum += __shfl_xor(ssum, msk, 64);
      const float inv = 1.0f / ssum;
      const int h = rt * 16 + grp * 4 + j;
      if (PMODE == 0) {
        od[h * 32 + lo]      = e0 * inv;
        od[h * 32 + 16 + lo] = e1 * inv;
      } else {
        ob[h * 32 + lo]      = f2bf(e0 * inv);
        ob[h * 32 + 16 + lo] = f2bf(e1 * inv);
      }
    }
  }
}

extern "C" void kernel_launch(void* const* d_in, const int* in_sizes, int n_in,
                              void* d_out, int out_size, void* d_ws, size_t ws_size,
                              hipStream_t stream) {
  const float* query = (const float*)d_in[0];
  const float* key   = (const float*)d_in[1];
  const float* value = (const float*)d_in[2];
  const float* Wq    = (const float*)d_in[3];
  const float* bq    = (const float*)d_in[4];
  const float* Wk    = (const float*)d_in[5];
  const float* bk    = (const float*)d_in[6];
  const float* Wv    = (const float*)d_in[7];
  const float* bv    = (const float*)d_in[8];

  const size_t P_BYTES = (size_t)32768 * 1024 * 2;   // 64 MB (p bf16)
  const size_t W_BYTES = (size_t)1024 * 1024 * 2;    // 2 MB per W
  unsigned short* pbf = (unsigned short*)d_ws;
  unsigned short* Wqb = (unsigned short*)((char*)d_ws + P_BYTES);
  unsigned short* Wkb = Wqb + (W_BYTES / 2);
  unsigned short* Wvb = Wkb + (W_BYTES / 2);

  if (ws_size >= P_BYTES + 3 * W_BYTES) {
    convw3_kernel<<<dim3(1536), dim3(256), 0, stream>>>(Wq, Wk, Wv, Wqb, Wkb, Wvb);
    gemm256<0><<<dim3(512), dim3(512), 0, stream>>>(query, Wqb, bq, d_out, pbf);
    gemm256<1><<<dim3(512), dim3(512), 0, stream>>>(key,   Wkb, bk, d_out, pbf);
    attn_kernel<1><<<dim3(8192), dim3(256), 0, stream>>>((float*)d_out, pbf);
    gemm256<2><<<dim3(512), dim3(512), 0, stream>>>(value, Wvb, bv, d_out, pbf);
  } else {
    const int use_ws = (ws_size >= P_BYTES) ? 1 : 0;
    gemm_fb<0><<<dim3(2048), dim3(256), 0, stream>>>(query, Wq, bq, d_out, nullptr, 0);
    gemm_fb<1><<<dim3(2048), dim3(256), 0, stream>>>(key,   Wk, bk, d_out, nullptr, 0);
    if (use_ws)
      attn_kernel<1><<<dim3(8192), dim3(256), 0, stream>>>((float*)d_out, pbf);
    else
      attn_kernel<0><<<dim3(8192), dim3(256), 0, stream>>>((float*)d_out, nullptr);
    gemm_fb<2><<<dim3(2048), dim3(256), 0, stream>>>(value, Wv, bv, d_out, pbf, use_ws);
  }
}

// Round 21
// 368.457 us; speedup vs baseline: 2.1183x; 1.0147x over previous
//
#include <hip/hip_runtime.h>
#include <hip/hip_bf16.h>

// B=4, S=8192 -> 32768 tokens; HID=1024; NH=DH=32.
// convw3: Wq/Wk/Wv f32 -> bf16 in d_ws (one 1536-block launch)
// S1qk: ONE 1024-block launch; blocks 0-511 q=(query@Wq^T+bq)/32,
//       blocks 512-1023 k=(key@Wk^T+bk); both -> bf16 in d_out regions
// S2  : per-token 32x32 scores + softmax over heads-t -> p bf16 @ d_ws
// S3  : v GEMM; epilogue out[idx] = p[idx] * (v+bv)
//
// GEMM core = r13 (session best, reproduced 3x at 378; r19 convw merge
// -> 374): 256² tile, BK=64, 8 waves (128x64 wave tile), bf16 LDS
// row*128+((s^(row&7))<<4) (0 conflicts), coalesced A staging (4 rows x
// 256B/instr), B via global_load_lds w16 pre-swizzled source, ONE raw
// s_barrier per K-step, counted vmcnt(8) (never 0 mid-loop), staging
// groups sched_barrier(0)-pinned (vmcnt contract needs pinned VMEM order).
// Rejected by experiment: 4-phase split (r16), LDS-depth+1 (r15),
// reg-depth+1 (r18, VGPR overflow), BK=32 2-blk/CU (r14, spill).
// r20 delta: q+k GEMMs merged into one launch (dispatch plumbing only;
// per-block operand select is wave-uniform SGPR work in the prologue).

typedef __attribute__((ext_vector_type(8))) short bf16x8;
typedef __attribute__((ext_vector_type(4))) float f32x4;

#define HID 1024

#define GLOAD_LDS16(gp, lp)                                                   \
  __builtin_amdgcn_global_load_lds(                                           \
      (const __attribute__((address_space(1))) void*)(gp),                    \
      (__attribute__((address_space(3))) void*)(lp), 16, 0, 0)

#define SBAR __builtin_amdgcn_sched_barrier(0)

__device__ __forceinline__ unsigned short f2bf(float f) {
  unsigned int u = __builtin_bit_cast(unsigned int, f);
  u += 0x7FFFu + ((u >> 16) & 1u);  // RTNE
  return (unsigned short)(u >> 16);
}
__device__ __forceinline__ float bf2f(unsigned short h) {
  unsigned int u = (unsigned int)h << 16;
  return __builtin_bit_cast(float, u);
}

__device__ __forceinline__ uint2 cvt4(f32x4 a) {
  uint2 r;
  asm("v_cvt_pk_bf16_f32 %0, %1, %2" : "=v"(r.x) : "v"(a[0]), "v"(a[1]));
  asm("v_cvt_pk_bf16_f32 %0, %1, %2" : "=v"(r.y) : "v"(a[2]), "v"(a[3]));
  return r;
}
__device__ __forceinline__ bf16x8 cvt8(f32x4 a, f32x4 b) {
  union { unsigned int u[4]; bf16x8 v; } r;
  asm("v_cvt_pk_bf16_f32 %0, %1, %2" : "=v"(r.u[0]) : "v"(a[0]), "v"(a[1]));
  asm("v_cvt_pk_bf16_f32 %0, %1, %2" : "=v"(r.u[1]) : "v"(a[2]), "v"(a[3]));
  asm("v_cvt_pk_bf16_f32 %0, %1, %2" : "=v"(r.u[2]) : "v"(b[0]), "v"(b[1]));
  asm("v_cvt_pk_bf16_f32 %0, %1, %2" : "=v"(r.u[3]) : "v"(b[2]), "v"(b[3]));
  return r.v;
}

// Wq/Wk/Wv f32 [1024][1024] -> bf16, one launch (1536 blocks of 256).
__global__ __launch_bounds__(256)
void convw3_kernel(const float* __restrict__ s0, const float* __restrict__ s1,
                   const float* __restrict__ s2, unsigned short* __restrict__ d0,
                   unsigned short* __restrict__ d1, unsigned short* __restrict__ d2) {
  const int w = blockIdx.x >> 9;               // 0,1,2 (wave-uniform)
  const int i = (blockIdx.x & 511) * 256 + threadIdx.x;
  const float* src = (w == 0) ? s0 : (w == 1) ? s1 : s2;
  unsigned short* dst = (w == 0) ? d0 : (w == 1) ? d1 : d2;
  const f32x4 a = ((const f32x4*)src)[i * 2];
  const f32x4 b = ((const f32x4*)src)[i * 2 + 1];
  ((bf16x8*)dst)[i] = cvt8(a, b);
}

// q+k projections in ONE launch. Blocks 0-511: q (scale 1/32, cols 0-1023
// of the token's 2048-u16 region); 512-1023: k (scale 1, cols 1024-2047).
__global__ __launch_bounds__(512, 1)
void gemm256qk(const float* __restrict__ Xq, const float* __restrict__ Xk,
               const unsigned short* __restrict__ Wqb,
               const unsigned short* __restrict__ Wkb,
               const float* __restrict__ bq, const float* __restrict__ bk,
               void* outp) {
  const int sel = blockIdx.x >> 9;             // 0 = q, 1 = k (wave-uniform)
  const float* X = sel ? Xk : Xq;
  const unsigned short* Wb = sel ? Wkb : Wqb;
  const float* bias = sel ? bk : bq;
  const float scale = sel ? 1.0f : 0.03125f;
  const int hoff = sel << 10;                  // 0 / 1024

  // 512 blocks = 128 m-tiles x 4 n-tiles; XCD-chunked, n fastest.
  const int bid = blockIdx.x & 511;
  const int L = (bid & 7) * 64 + (bid >> 3);
  const int m0 = (L >> 2) * 256;
  const int n0 = (L & 3) * 256;
  const int tid = threadIdx.x;
  const int lane = tid & 63;
  const int wid = tid >> 6;
  const int wm = (wid >> 2) * 128;
  const int wn = (wid & 3) * 64;
  const int lo = lane & 15, grp = lane >> 4;

  __shared__ __align__(16) unsigned char lds[2][65536];

  const char* Xc = (const char*)X;
  const int acg = tid & 15;
  size_t asrc[8]; int aldst[8];
#pragma unroll
  for (int i = 0; i < 8; ++i) {
    const int row = i * 32 + (tid >> 4);
    asrc[i] = (size_t)(m0 + row) * 4096 + (size_t)(acg * 16);
    aldst[i] = row * 128 + (((acg >> 1) ^ (row & 7)) << 4) + (acg & 1) * 8;
  }
  f32x4 ar[8];
  auto aload = [&](int kt) {
    const size_t kb = (size_t)kt * 256;
#pragma unroll
    for (int i = 0; i < 8; ++i) ar[i] = *(const f32x4*)(Xc + asrc[i] + kb);
  };
  auto awrite = [&](int b) {
#pragma unroll
    for (int i = 0; i < 8; ++i) *(uint2*)&lds[b][aldst[i]] = cvt4(ar[i]);
  };

  const char* Wc = (const char*)Wb;
  size_t bsrc[4];
#pragma unroll
  for (int i = 0; i < 4; ++i) {
    const int g = tid + i * 512;
    const int row = g >> 3, j = g & 7;
    bsrc[i] = (size_t)(n0 + row) * 2048 + (size_t)((j ^ (row & 7)) << 4);
  }
  auto bstage = [&](int b, int kt) {
    const size_t kb = (size_t)kt * 128;
#pragma unroll
    for (int i = 0; i < 4; ++i)
      GLOAD_LDS16(Wc + bsrc[i] + kb, &lds[b][32768 + tid * 16 + i * 8192]);
  };

  f32x4 acc[8][4] = {};
  auto compute = [&](int b) {
#pragma unroll
    for (int kk = 0; kk < 2; ++kk) {
      const int s = kk * 4 + grp;
      bf16x8 af[8], bfm[4];
#pragma unroll
      for (int f = 0; f < 8; ++f) {
        const int ra = wm + f * 16 + lo;
        af[f] = *(const bf16x8*)&lds[b][ra * 128 + ((s ^ (ra & 7)) << 4)];
      }
#pragma unroll
      for (int g = 0; g < 4; ++g) {
        const int rb = wn + g * 16 + lo;
        bfm[g] = *(const bf16x8*)&lds[b][32768 + rb * 128 + ((s ^ (rb & 7)) << 4)];
      }
      __builtin_amdgcn_s_setprio(1);
#pragma unroll
      for (int fm = 0; fm < 8; ++fm)
#pragma unroll
        for (int fn = 0; fn < 4; ++fn)
          acc[fm][fn] = __builtin_amdgcn_mfma_f32_16x16x32_bf16(
              af[fm], bfm[fn], acc[fm][fn], 0, 0, 0);
      __builtin_amdgcn_s_setprio(0);
    }
  };

  // Prologue: tile0 staged; aload(1) left in flight. Order PINNED.
  aload(0);
  awrite(0);
  SBAR;
  bstage(0, 0);
  SBAR;
  aload(1);
  SBAR;
  asm volatile("s_waitcnt vmcnt(8)" ::: "memory");
  asm volatile("s_waitcnt lgkmcnt(0)" ::: "memory");
  __builtin_amdgcn_s_barrier();
  SBAR;

#pragma unroll 1
  for (int kt = 0; kt < 16; ++kt) {
    const int cur = kt & 1;
    if (kt < 15) {
      awrite(cur ^ 1);
      SBAR;
      bstage(cur ^ 1, kt + 1);
      SBAR;
      if (kt < 14) aload(kt + 2);
      SBAR;
    }
    compute(cur);
    SBAR;
    if (kt < 14) asm volatile("s_waitcnt vmcnt(8)" ::: "memory");
    else         asm volatile("s_waitcnt vmcnt(0)" ::: "memory");
    asm volatile("s_waitcnt lgkmcnt(0)" ::: "memory");
    __builtin_amdgcn_s_barrier();
    SBAR;
  }

  // Epilogue (bf16 staged in LDS, contiguous stores).
  {
    unsigned short* lds16 = (unsigned short*)&lds[0][0];  // [128][256]
    unsigned short* ob = (unsigned short*)outp;
    float bcol[4];
#pragma unroll
    for (int fn = 0; fn < 4; ++fn) bcol[fn] = bias[n0 + wn + fn * 16 + lo];
#pragma unroll 1
    for (int h = 0; h < 2; ++h) {
      if ((wid >> 2) == h) {
#pragma unroll
        for (int fm = 0; fm < 8; ++fm)
#pragma unroll
          for (int fn = 0; fn < 4; ++fn)
#pragma unroll
            for (int j = 0; j < 4; ++j) {
              const int rl = fm * 16 + grp * 4 + j;
              const int col = wn + fn * 16 + lo;
              lds16[rl * 256 + (col ^ (grp << 4))] =
                  f2bf((acc[fm][fn][j] + bcol[fn]) * scale);
            }
      }
      __syncthreads();
      {
        const int row = tid >> 2;
        const int c0 = (tid & 3) * 64;
        const int x = ((row >> 2) & 3) << 4;
#pragma unroll
        for (int q = 0; q < 8; ++q) {
          const int cg = c0 + q * 8;
          const uint4 v = *(const uint4*)&lds16[row * 256 + (cg ^ x)];
          *(uint4*)&ob[(size_t)(m0 + h * 128 + row) * 2048 + hoff + n0 + cg] = v;
        }
      }
      __syncthreads();
    }
  }
}

// v GEMM: out[idx] = p[idx] * (v@Wv^T + bv)[idx]
__global__ __launch_bounds__(512, 1)
void gemm256v(const float* __restrict__ X, const unsigned short* __restrict__ Wb,
              const float* __restrict__ bias, void* outp,
              const unsigned short* __restrict__ pbf) {
  const int bid = blockIdx.x;
  const int L = (bid & 7) * 64 + (bid >> 3);
  const int m0 = (L >> 2) * 256;
  const int n0 = (L & 3) * 256;
  const int tid = threadIdx.x;
  const int lane = tid & 63;
  const int wid = tid >> 6;
  const int wm = (wid >> 2) * 128;
  const int wn = (wid & 3) * 64;
  const int lo = lane & 15, grp = lane >> 4;

  __shared__ __align__(16) unsigned char lds[2][65536];

  const char* Xc = (const char*)X;
  const int acg = tid & 15;
  size_t asrc[8]; int aldst[8];
#pragma unroll
  for (int i = 0; i < 8; ++i) {
    const int row = i * 32 + (tid >> 4);
    asrc[i] = (size_t)(m0 + row) * 4096 + (size_t)(acg * 16);
    aldst[i] = row * 128 + (((acg >> 1) ^ (row & 7)) << 4) + (acg & 1) * 8;
  }
  f32x4 ar[8];
  auto aload = [&](int kt) {
    const size_t kb = (size_t)kt * 256;
#pragma unroll
    for (int i = 0; i < 8; ++i) ar[i] = *(const f32x4*)(Xc + asrc[i] + kb);
  };
  auto awrite = [&](int b) {
#pragma unroll
    for (int i = 0; i < 8; ++i) *(uint2*)&lds[b][aldst[i]] = cvt4(ar[i]);
  };

  const char* Wc = (const char*)Wb;
  size_t bsrc[4];
#pragma unroll
  for (int i = 0; i < 4; ++i) {
    const int g = tid + i * 512;
    const int row = g >> 3, j = g & 7;
    bsrc[i] = (size_t)(n0 + row) * 2048 + (size_t)((j ^ (row & 7)) << 4);
  }
  auto bstage = [&](int b, int kt) {
    const size_t kb = (size_t)kt * 128;
#pragma unroll
    for (int i = 0; i < 4; ++i)
      GLOAD_LDS16(Wc + bsrc[i] + kb, &lds[b][32768 + tid * 16 + i * 8192]);
  };

  f32x4 acc[8][4] = {};
  auto compute = [&](int b) {
#pragma unroll
    for (int kk = 0; kk < 2; ++kk) {
      const int s = kk * 4 + grp;
      bf16x8 af[8], bfm[4];
#pragma unroll
      for (int f = 0; f < 8; ++f) {
        const int ra = wm + f * 16 + lo;
        af[f] = *(const bf16x8*)&lds[b][ra * 128 + ((s ^ (ra & 7)) << 4)];
      }
#pragma unroll
      for (int g = 0; g < 4; ++g) {
        const int rb = wn + g * 16 + lo;
        bfm[g] = *(const bf16x8*)&lds[b][32768 + rb * 128 + ((s ^ (rb & 7)) << 4)];
      }
      __builtin_amdgcn_s_setprio(1);
#pragma unroll
      for (int fm = 0; fm < 8; ++fm)
#pragma unroll
        for (int fn = 0; fn < 4; ++fn)
          acc[fm][fn] = __builtin_amdgcn_mfma_f32_16x16x32_bf16(
              af[fm], bfm[fn], acc[fm][fn], 0, 0, 0);
      __builtin_amdgcn_s_setprio(0);
    }
  };

  aload(0);
  awrite(0);
  SBAR;
  bstage(0, 0);
  SBAR;
  aload(1);
  SBAR;
  asm volatile("s_waitcnt vmcnt(8)" ::: "memory");
  asm volatile("s_waitcnt lgkmcnt(0)" ::: "memory");
  __builtin_amdgcn_s_barrier();
  SBAR;

#pragma unroll 1
  for (int kt = 0; kt < 16; ++kt) {
    const int cur = kt & 1;
    if (kt < 15) {
      awrite(cur ^ 1);
      SBAR;
      bstage(cur ^ 1, kt + 1);
      SBAR;
      if (kt < 14) aload(kt + 2);
      SBAR;
    }
    compute(cur);
    SBAR;
    if (kt < 14) asm volatile("s_waitcnt vmcnt(8)" ::: "memory");
    else         asm volatile("s_waitcnt vmcnt(0)" ::: "memory");
    asm volatile("s_waitcnt lgkmcnt(0)" ::: "memory");
    __builtin_amdgcn_s_barrier();
    SBAR;
  }

  float* of = (float*)outp;
#pragma unroll
  for (int fm = 0; fm < 8; ++fm) {
    const int row = m0 + wm + fm * 16 + grp * 4;
#pragma unroll
    for (int fn = 0; fn < 4; ++fn) {
      const int col = n0 + wn + fn * 16 + lo;
      const float bc = bias[col];
#pragma unroll
      for (int j = 0; j < 4; ++j) {
        const size_t idx = (size_t)(row + j) * 1024 + col;
        of[idx] = bf2f(pbf[idx]) * (acc[fm][fn][j] + bc);
      }
    }
  }
}

// ---------- fallback GEMM (used only if ws too small) ----------
template<int MODE>
__global__ __launch_bounds__(256, 2)
void gemm_fb(const float* __restrict__ X, const float* __restrict__ W,
             const float* __restrict__ bias, void* outp,
             const unsigned short* __restrict__ pbf, int use_ws) {
  const int bid = blockIdx.x;
  const int L = (bid & 7) * 256 + (bid >> 3);
  const int m0 = (L >> 3) * 128;
  const int n0 = (L & 7) * 128;
  const int tid = threadIdx.x;
  const int lane = tid & 63;
  const int wid = tid >> 6;
  const int wm = (wid >> 1) << 6;
  const int wn = (wid & 1) << 6;
  const int lo = lane & 15, grp = lane >> 4;
  __shared__ __align__(16) unsigned char lds[2][32768];
  const int srow = tid >> 3;
  const int sk8  = tid & 7;
  const float* Ag = X + (size_t)(m0 + srow) * HID + sk8 * 8;
  const float* Bg = W + (size_t)(n0 + srow) * HID + sk8 * 8;
  f32x4 la[4][2], lb[4][2];
  auto gload = [&](int k0) {
#pragma unroll
    for (int rr = 0; rr < 4; ++rr) {
      const float* ap = Ag + (size_t)(rr * 32) * HID + k0;
      const float* bp = Bg + (size_t)(rr * 32) * HID + k0;
      la[rr][0] = *(const f32x4*)(ap); la[rr][1] = *(const f32x4*)(ap + 4);
      lb[rr][0] = *(const f32x4*)(bp); lb[rr][1] = *(const f32x4*)(bp + 4);
    }
  };
  auto cvtwrite = [&](int b) {
#pragma unroll
    for (int rr = 0; rr < 4; ++rr) {
      const int row = srow + rr * 32;
      const int adr = row * 128 + ((sk8 ^ (row & 7)) << 4);
      *(bf16x8*)&lds[b][adr]         = cvt8(la[rr][0], la[rr][1]);
      *(bf16x8*)&lds[b][16384 + adr] = cvt8(lb[rr][0], lb[rr][1]);
    }
  };
  f32x4 acc[4][4] = {};
  auto compute = [&](int b) {
#pragma unroll
    for (int kk = 0; kk < 2; ++kk) {
      const int slot = kk * 4 + grp;
      bf16x8 af[4], bfm[4];
#pragma unroll
      for (int f = 0; f < 4; ++f) {
        const int ra = wm + f * 16 + lo;
        const int rb = wn + f * 16 + lo;
        af[f]  = *(const bf16x8*)&lds[b][ra * 128 + ((slot ^ (ra & 7)) << 4)];
        bfm[f] = *(const bf16x8*)&lds[b][16384 + rb * 128 + ((slot ^ (rb & 7)) << 4)];
      }
#pragma unroll
      for (int fm = 0; fm < 4; ++fm)
#pragma unroll
        for (int fn = 0; fn < 4; ++fn)
          acc[fm][fn] = __builtin_amdgcn_mfma_f32_16x16x32_bf16(
              af[fm], bfm[fn], acc[fm][fn], 0, 0, 0);
    }
  };
  gload(0); cvtwrite(0); gload(64);
  SBAR;
  asm volatile("s_waitcnt lgkmcnt(0)" ::: "memory");
  __builtin_amdgcn_s_barrier();
  SBAR;
#pragma unroll 1
  for (int kt = 0; kt < 16; ++kt) {
    compute(kt & 1);
    if (kt < 15) {
      cvtwrite((kt + 1) & 1);
      if (kt < 14) gload((kt + 2) * 64);
    }
    SBAR;
    asm volatile("s_waitcnt lgkmcnt(0)" ::: "memory");
    __builtin_amdgcn_s_barrier();
    SBAR;
  }
  unsigned char* eb = &lds[0][0];
  const unsigned char* ebc = eb;
  if (MODE == 2) {
    float* of = (float*)outp;
#pragma unroll
    for (int fm = 0; fm < 4; ++fm) {
      const int row = m0 + wm + fm * 16 + grp * 4;
#pragma unroll
      for (int fn = 0; fn < 4; ++fn) {
        const int col = n0 + wn + fn * 16 + lo;
        const float bc = bias[col];
#pragma unroll
        for (int j = 0; j < 4; ++j) {
          const size_t idx = (size_t)(row + j) * 1024 + col;
          const float p = use_ws ? bf2f(pbf[idx]) : of[idx];
          of[idx] = p * (acc[fm][fn][j] + bc);
        }
      }
    }
  } else {
    const float scale = (MODE == 0) ? 0.03125f : 1.0f;
#pragma unroll
    for (int fm = 0; fm < 4; ++fm) {
#pragma unroll
      for (int fn = 0; fn < 4; ++fn) {
        const int colL = wn + fn * 16 + lo;
        const float bc = bias[n0 + colL];
#pragma unroll
        for (int j = 0; j < 4; ++j) {
          const int rowL = wm + fm * 16 + grp * 4 + j;
          const int byte = rowL * 256 + ((colL * 2) ^ ((rowL & 7) << 5));
          *(unsigned short*)&eb[byte] = f2bf((acc[fm][fn][j] + bc) * scale);
        }
      }
    }
    __syncthreads();
    unsigned short* ob = (unsigned short*)outp;
    const int hoff = (MODE == 1) ? 1024 : 0;
#pragma unroll
    for (int p = 0; p < 8; ++p) {
      const int r = p * 16 + (tid >> 4);
      const int c0 = (tid & 15) * 8;
      const uint4 v = *(const uint4*)&ebc[r * 256 + ((c0 * 2) ^ ((r & 7) << 5))];
      *(uint4*)&ob[(size_t)(m0 + r) * 2048 + hoff + n0 + c0] = v;
    }
  }
}

// S2: one wave per token. 32x32 scores via 4 MFMA, softmax over t (cols).
template<int PMODE>
__global__ __launch_bounds__(256)
void attn_kernel(float* __restrict__ dout, unsigned short* __restrict__ wsp) {
  const int wid = threadIdx.x >> 6;
  const int lane = threadIdx.x & 63;
  const int token = blockIdx.x * 4 + wid;
  const int lo = lane & 15, grp = lane >> 4;
  const unsigned short* qk = (const unsigned short*)dout + (size_t)token * 2048;
  const int base = lo * 32 + grp * 8;

  bf16x8 a0 = *(const bf16x8*)(qk + base);
  bf16x8 a1 = *(const bf16x8*)(qk + 512 + base);
  bf16x8 b0 = *(const bf16x8*)(qk + 1024 + base);
  bf16x8 b1 = *(const bf16x8*)(qk + 1536 + base);
  asm volatile("s_waitcnt vmcnt(0)" ::: "memory");

  const f32x4 z = {0.f, 0.f, 0.f, 0.f};
  f32x4 s[2][2];
  s[0][0] = __builtin_amdgcn_mfma_f32_16x16x32_bf16(a0, b0, z, 0, 0, 0);
  s[0][1] = __builtin_amdgcn_mfma_f32_16x16x32_bf16(a0, b1, z, 0, 0, 0);
  s[1][0] = __builtin_amdgcn_mfma_f32_16x16x32_bf16(a1, b0, z, 0, 0, 0);
  s[1][1] = __builtin_amdgcn_mfma_f32_16x16x32_bf16(a1, b1, z, 0, 0, 0);

  float* od = dout + (size_t)token * 1024;
  unsigned short* ob = wsp + (size_t)token * 1024;
#pragma unroll
  for (int rt = 0; rt < 2; ++rt) {
#pragma unroll
    for (int j = 0; j < 4; ++j) {
      const float v0 = s[rt][0][j], v1 = s[rt][1][j];
      float m = fmaxf(v0, v1);
#pragma unroll
      for (int msk = 1; msk < 16; msk <<= 1) m = fmaxf(m, __shfl_xor(m, msk, 64));
      const float e0 = __expf(v0 - m), e1 = __expf(v1 - m);
      float ssum = e0 + e1;
#pragma unroll
      for (int msk = 1; msk < 16; msk <<= 1) ssum += __shfl_xor(ssum, msk, 64);
      const float inv = 1.0f / ssum;
      const int h = rt * 16 + grp * 4 + j;
      if (PMODE == 0) {
        od[h * 32 + lo]      = e0 * inv;
        od[h * 32 + 16 + lo] = e1 * inv;
      } else {
        ob[h * 32 + lo]      = f2bf(e0 * inv);
        ob[h * 32 + 16 + lo] = f2bf(e1 * inv);
      }
    }
  }
}

extern "C" void kernel_launch(void* const* d_in, const int* in_sizes, int n_in,
                              void* d_out, int out_size, void* d_ws, size_t ws_size,
                              hipStream_t stream) {
  const float* query = (const float*)d_in[0];
  const float* key   = (const float*)d_in[1];
  const float* value = (const float*)d_in[2];
  const float* Wq    = (const float*)d_in[3];
  const float* bq    = (const float*)d_in[4];
  const float* Wk    = (const float*)d_in[5];
  const float* bk    = (const float*)d_in[6];
  const float* Wv    = (const float*)d_in[7];
  const float* bv    = (const float*)d_in[8];

  const size_t P_BYTES = (size_t)32768 * 1024 * 2;   // 64 MB (p bf16)
  const size_t W_BYTES = (size_t)1024 * 1024 * 2;    // 2 MB per W
  unsigned short* pbf = (unsigned short*)d_ws;
  unsigned short* Wqb = (unsigned short*)((char*)d_ws + P_BYTES);
  unsigned short* Wkb = Wqb + (W_BYTES / 2);
  unsigned short* Wvb = Wkb + (W_BYTES / 2);

  if (ws_size >= P_BYTES + 3 * W_BYTES) {
    convw3_kernel<<<dim3(1536), dim3(256), 0, stream>>>(Wq, Wk, Wv, Wqb, Wkb, Wvb);
    gemm256qk<<<dim3(1024), dim3(512), 0, stream>>>(query, key, Wqb, Wkb, bq, bk, d_out);
    attn_kernel<1><<<dim3(8192), dim3(256), 0, stream>>>((float*)d_out, pbf);
    gemm256v<<<dim3(512), dim3(512), 0, stream>>>(value, Wvb, bv, d_out, pbf);
  } else {
    const int use_ws = (ws_size >= P_BYTES) ? 1 : 0;
    gemm_fb<0><<<dim3(2048), dim3(256), 0, stream>>>(query, Wq, bq, d_out, nullptr, 0);
    gemm_fb<1><<<dim3(2048), dim3(256), 0, stream>>>(key,   Wk, bk, d_out, nullptr, 0);
    if (use_ws)
      attn_kernel<1><<<dim3(8192), dim3(256), 0, stream>>>((float*)d_out, pbf);
    else
      attn_kernel<0><<<dim3(8192), dim3(256), 0, stream>>>((float*)d_out, nullptr);
    gemm_fb<2><<<dim3(2048), dim3(256), 0, stream>>>(value, Wv, bv, d_out, pbf, use_ws);
  }
}